// Round 19
// baseline (229.630 us; speedup 1.0000x reference)
//
#include <hip/hip_runtime.h>

typedef unsigned short u16;
typedef unsigned int u32;

#define HW 256
#define PIX 65536

// workspace byte offsets
#define WS_T1   100663296ull
#define WS_K1   134217728ull
#define WS_VP   167772160ull
#define WS_NEED 201326592ull

typedef __attribute__((ext_vector_type(8))) short s8v;   // 8 bf16
typedef __attribute__((ext_vector_type(4))) float f4v;

__device__ __forceinline__ float bu2f(u16 u){ union{u32 i; float f;} x; x.i=((u32)u)<<16; return x.f; }
__device__ __forceinline__ u16 f2bu(float f){ union{float f; u32 i;} x; x.f=f; u32 i=x.i; return (u16)((i + 0x7FFFu + ((i>>16)&1u))>>16); }
__device__ __forceinline__ float sigm(float x){ return 1.0f/(1.0f+__expf(-x)); }
__device__ __forceinline__ u16 cvt_el(float v){ return f2bu(v); }
__device__ __forceinline__ u16 cvt_el(u16 v){ return v; }
// XOR swizzle for [R][256] u16 tiles (8-elem block granularity)
__device__ __forceinline__ int swz(int r, int c){ return r*256 + (((c>>3) ^ (r&7))<<3) + (c&7); }
// XOR swizzle for [256 p][128 c] u16 tiles (same family, stride 128)
__device__ __forceinline__ int pswz(int p, int c){ return (p<<7) + (((c>>3) ^ (p&7))<<3) + (c&7); }
// Vt subtile layout: conflict-free for both transpose-write and PV b-frag read
__device__ __forceinline__ int vt_el(int w, int gb){   // gb = g>>3
  int q = (w & 15) ^ gb ^ ((w >> 4) & 7);
  return ((w >> 4) << 10) + (gb << 7) + (q << 3);
}

// ---------------- weight prep: fp32 -> bf16, pre-swizzled to the GEMM's Wl image ----------------
__global__ __launch_bounds__(256) void k_wprep(const float* __restrict__ Wg, u16* __restrict__ G, int n){
  int i = blockIdx.x * 256 + threadIdx.x;
  if (i >= n) return;
  int o = i >> 7, c = i & 127;
  G[(o << 7) | (c ^ ((o & 7) << 3))] = f2bu(Wg[i]);
}

// ---------------- fused MFMA GEMM over plane-layout input (8 waves) ----------------
template<int OC, typename TIN, bool F32>
__global__ __launch_bounds__(512,1) void k_gemmP2(const TIN* __restrict__ in, const u16* __restrict__ Wbf,
                                                  const float* __restrict__ bias, int O_total,
                                                  void* __restrict__ outv){
  extern __shared__ u16 lds[];
  u16* Wl = lds;                 // [OC][128] swizzled (c ^ (o&7)<<3)
  u16* Xl = lds + OC*128;        // [256 p][128 c] pswz
  int t = threadIdx.x;
  {
    const uint4* Wq4 = (const uint4*)Wbf;
    uint4* Wl4 = (uint4*)Wl;
    #pragma unroll
    for (int i = t; i < OC*16; i += 512) Wl4[i] = Wq4[i];
  }
  int p_blk = blockIdx.x * 256;
  int b = p_blk >> 16;
  int p0 = p_blk & 65535;
  if (sizeof(TIN) == 4){
    int p = t & 255, half = (t >> 8) * 64;
    const float* col = (const float*)in + ((size_t)(b*128 + half))*PIX + p0 + p;
    #pragma unroll
    for (int c8 = 0; c8 < 8; ++c8){
      u32 pk[4];
      #pragma unroll
      for (int j = 0; j < 4; ++j){
        u16 v0 = f2bu(col[(size_t)(c8*8 + 2*j)*PIX]);
        u16 v1 = f2bu(col[(size_t)(c8*8 + 2*j + 1)*PIX]);
        pk[j] = (u32)v0 | ((u32)v1 << 16);
      }
      *(uint4*)(Xl + pswz(p, half + c8*8)) = make_uint4(pk[0],pk[1],pk[2],pk[3]);
    }
  } else {
    int p = (t & 127) * 2, quarter = (t >> 7) * 32;
    const u16* col = (const u16*)in + ((size_t)(b*128 + quarter))*PIX + p0 + p;
    #pragma unroll
    for (int c8 = 0; c8 < 4; ++c8){
      u32 va[4], vb[4];
      #pragma unroll
      for (int j = 0; j < 4; ++j){
        u32 w0 = *(const u32*)(col + (size_t)(c8*8 + 2*j)*PIX);
        u32 w1 = *(const u32*)(col + (size_t)(c8*8 + 2*j + 1)*PIX);
        va[j] = (w0 & 0xFFFFu) | (w1 << 16);
        vb[j] = (w0 >> 16) | (w1 & 0xFFFF0000u);
      }
      *(uint4*)(Xl + pswz(p,     quarter + c8*8)) = make_uint4(va[0],va[1],va[2],va[3]);
      *(uint4*)(Xl + pswz(p + 1, quarter + c8*8)) = make_uint4(vb[0],vb[1],vb[2],vb[3]);
    }
  }
  __syncthreads();

  int wv = t >> 6, l = t & 63;
  int lg = l >> 4, lr = l & 15;
  int p_in0 = p0 + wv*32 + lr;

  s8v bf[2][4];
  #pragma unroll
  for (int pt = 0; pt < 2; ++pt){
    int p = wv*32 + pt*16 + lr;
    #pragma unroll
    for (int ks = 0; ks < 4; ++ks)
      bf[pt][ks] = *(const s8v*)(Xl + pswz(p, ks*32 + lg*8));
  }

  for (int ot = 0; ot < OC / 16; ++ot){
    f4v acc[2];
    acc[0] = (f4v){0.f,0.f,0.f,0.f};
    acc[1] = (f4v){0.f,0.f,0.f,0.f};
    int o = (ot << 4) + lr;
    const u16* wl = Wl + (o << 7);
    int sw = (o & 7) << 3;
    #pragma unroll
    for (int ks = 0; ks < 4; ++ks){
      s8v a = *(const s8v*)(wl + ((((ks << 5) + (lg << 3)) ^ sw)));
      acc[0] = __builtin_amdgcn_mfma_f32_16x16x32_bf16(a, bf[0][ks], acc[0], 0, 0, 0);
      acc[1] = __builtin_amdgcn_mfma_f32_16x16x32_bf16(a, bf[1][ks], acc[1], 0, 0, 0);
    }
    #pragma unroll
    for (int j = 0; j < 4; ++j){
      int o_row = (ot << 4) + (lg << 2) + j;
      float bv = bias[o_row];
      size_t base = ((size_t)(b * O_total + o_row)) << 16;
      #pragma unroll
      for (int pt = 0; pt < 2; ++pt){
        if (F32){
          ((float*)outv)[base + p_in0 + pt*16] = acc[pt][j] + bv;
        } else {
          ((u16*)outv)[base + p_in0 + pt*16] = f2bu(acc[pt][j] + bv);
        }
      }
    }
  }
}
#define GP384_LDS ((384*128 + 256*128) * 2)   // 163840
#define GP128_LDS ((128*128 + 256*128) * 2)   // 98304

// ---------------- depthwise 3x3 on q,k + fused row L2-normalize (LDS tiled) ----------------
__global__ __launch_bounds__(256) void k_dwqk2(const u16* __restrict__ qkv,
                                               const float* __restrict__ w_q, const float* __restrict__ b_q,
                                               const float* __restrict__ w_k, const float* __restrict__ b_k,
                                               u16* __restrict__ q1, u16* __restrict__ k1){
  __shared__ u16 ins[18*272];
  int t = threadIdx.x;
  int chunk = blockIdx.x;
  int c = blockIdx.y;
  int which = blockIdx.z & 1, b = blockIdx.z >> 1;
  const u16* in = qkv + ((size_t)(b*384 + which*128 + c)) * PIX;

  #pragma unroll
  for (int i = t; i < 612; i += 256) ((uint4*)ins)[i] = make_uint4(0,0,0,0);
  __syncthreads();
  int r0 = chunk*16 - 1;
  for (int i = t; i < 576; i += 256){
    int j = i >> 5, k = i & 31;
    int r = r0 + j;
    if (r >= 0 && r < HW)
      *(uint4*)(ins + j*272 + 8 + k*8) = *(const uint4*)(in + r*HW + k*8);
  }
  __syncthreads();

  const float* wk = (which ? w_k : w_q) + c*9;
  float K0=wk[0],K1=wk[1],K2=wk[2],K3=wk[3],K4=wk[4],K5=wk[5],K6=wk[6],K7=wk[7],K8=wk[8];
  float bias = (which ? b_k : b_q)[c];

  int wv = t >> 6, l = t & 63;
  int cb = l * 4;
  float wr[3][6];
  auto ldrow = [&](int j, int slot){
    ushort4 m = *(const ushort4*)(ins + j*272 + 8 + cb);
    wr[slot][0] = bu2f(ins[j*272 + 7 + cb]);
    wr[slot][1] = bu2f(m.x); wr[slot][2] = bu2f(m.y);
    wr[slot][3] = bu2f(m.z); wr[slot][4] = bu2f(m.w);
    wr[slot][5] = bu2f(ins[j*272 + 12 + cb]);
  };
  int rb = wv * 4;
  ldrow(rb, 0); ldrow(rb+1, 1);
  u16* outp = (which ? k1 : q1) + ((size_t)(b*128 + c)) * PIX;
  #pragma unroll
  for (int s = 0; s < 4; ++s){
    ldrow(rb + s + 2, (s+2)%3);
    const float* T = wr[s%3];
    const float* M = wr[(s+1)%3];
    const float* Bo = wr[(s+2)%3];
    float o[4]; float ss = 0.f;
    #pragma unroll
    for (int d = 0; d < 4; ++d){
      float a = bias;
      a = fmaf(K0, T[d], a);  a = fmaf(K1, T[d+1], a);  a = fmaf(K2, T[d+2], a);
      a = fmaf(K3, M[d], a);  a = fmaf(K4, M[d+1], a);  a = fmaf(K5, M[d+2], a);
      a = fmaf(K6, Bo[d], a); a = fmaf(K7, Bo[d+1], a); a = fmaf(K8, Bo[d+2], a);
      o[d] = a;
      ss = fmaf(a, a, ss);
    }
    #pragma unroll
    for (int m = 1; m < 64; m <<= 1) ss += __shfl_xor(ss, m, 64);
    float sc = 1.0f / fmaxf(sqrtf(ss), 1e-12f);
    int row = chunk*16 + rb + s;
    ushort4 pk;
    pk.x = f2bu(o[0]*sc); pk.y = f2bu(o[1]*sc); pk.z = f2bu(o[2]*sc); pk.w = f2bu(o[3]*sc);
    *(ushort4*)(outp + row*HW + cb) = pk;
  }
}

// ---------------- MDC on v (LDS tiled, 32-row chunks) ----------------
#define MDC_LDS (2*36*272*2 + 34*272*4)   // 76160 B

__global__ __launch_bounds__(256,1) void k_mdc2(const u16* __restrict__ qkv,
                                                const float* __restrict__ w_v1, const float* __restrict__ b_v1,
                                                const float* __restrict__ w_v2, const float* __restrict__ b_v2,
                                                u16* __restrict__ vp){
  extern __shared__ char sm[];
  u16*   ins = (u16*)sm;                       // [2 ch][36 rows][272]
  float* x1s = (float*)(sm + 2*36*272*2);      // [34 rows][272]
  int t = threadIdx.x;
  int chunk = blockIdx.x;
  int g = blockIdx.y;
  int b = blockIdx.z;
  const u16* vbase = qkv + ((size_t)(b*384 + 256)) * PIX;

  #pragma unroll
  for (int i = t; i < 2*36*34; i += 256) ((uint4*)ins)[i] = make_uint4(0,0,0,0);
  for (int i = t; i < 34*68; i += 256) ((uint4*)x1s)[i] = make_uint4(0,0,0,0);
  __syncthreads();
  int r0 = chunk*32 - 2;
  #pragma unroll
  for (int ch = 0; ch < 2; ++ch){
    const u16* src = vbase + (size_t)(2*g + ch) * PIX;
    for (int i = t; i < 1152; i += 256){
      int j = i >> 5, k = i & 31;
      int r = r0 + j;
      if (r >= 0 && r < HW)
        *(uint4*)(ins + ch*36*272 + j*272 + 8 + k*8) = *(const uint4*)(src + r*HW + k*8);
    }
  }
  __syncthreads();

  float W1[18];
  #pragma unroll
  for (int i = 0; i < 18; ++i) W1[i] = w_v1[g*18 + i];
  float B1 = b_v1[g];
  int cb = t + 8;
  float win[2][3][3];
  #pragma unroll
  for (int ch = 0; ch < 2; ++ch)
    #pragma unroll
    for (int rr = 0; rr < 2; ++rr)
      #pragma unroll
      for (int k = 0; k < 3; ++k)
        win[ch][rr][k] = bu2f(ins[ch*36*272 + rr*272 + cb - 1 + k]);
  #pragma unroll
  for (int j = 0; j < 34; ++j){
    #pragma unroll
    for (int ch = 0; ch < 2; ++ch)
      #pragma unroll
      for (int k = 0; k < 3; ++k)
        win[ch][(j+2)%3][k] = bu2f(ins[ch*36*272 + (j+2)*272 + cb - 1 + k]);
    float v = B1;
    #pragma unroll
    for (int ch = 0; ch < 2; ++ch)
      #pragma unroll
      for (int i = 0; i < 3; ++i)
        #pragma unroll
        for (int k = 0; k < 3; ++k)
          v = fmaf(W1[ch*9 + i*3 + k], win[ch][(j+i)%3][k], v);
    int gr = chunk*32 - 1 + j;
    if (gr >= 0 && gr < HW) x1s[j*272 + cb] = v;
  }
  __syncthreads();

  float W2[9];
  #pragma unroll
  for (int i = 0; i < 9; ++i) W2[i] = w_v2[g*9 + i];
  float B2 = b_v2[g];
  const u16* vg   = vbase + (size_t)g * PIX;
  const u16* vg64 = vbase + (size_t)(64 + g) * PIX;
  u16* out0 = vp + ((size_t)(b*128 + g)) * PIX;
  u16* out1 = vp + ((size_t)(b*128 + 64 + g)) * PIX;
  float xw[3][3];
  #pragma unroll
  for (int rr = 0; rr < 2; ++rr)
    #pragma unroll
    for (int k = 0; k < 3; ++k)
      xw[rr][k] = x1s[rr*272 + cb - 1 + k];
  #pragma unroll
  for (int h = 0; h < 32; ++h){
    #pragma unroll
    for (int k = 0; k < 3; ++k)
      xw[(h+2)%3][k] = x1s[(h+2)*272 + cb - 1 + k];
    float x2 = B2;
    #pragma unroll
    for (int i = 0; i < 3; ++i)
      #pragma unroll
      for (int k = 0; k < 3; ++k)
        x2 = fmaf(W2[i*3 + k], xw[(h+i)%3][k], x2);
    int gr = chunk*32 + h;
    float g1 = sigm(bu2f(vg[gr*HW + t]));
    float g2 = sigm(bu2f(vg64[gr*HW + t]));
    float x1c = xw[(h+1)%3][1];
    out0[gr*HW + t] = f2bu(g1 * x1c);
    out1[gr*HW + t] = f2bu(g2 * x2);
  }
}

// ---------------- MFMA per-(b,c) row attention (K-dbuf QK + XCD-grouped blocks) ----------------
// block = (plane, half of 128 q-rows); 512 blocks x 512 threads, 160KB LDS
// XCD swizzle: logical blk = ((n&7)<<6)|(n>>3) — each XCD gets 64 consecutive logical blocks
// (32 whole planes), so both halves of a plane run on the SAME XCD and share L2-resident K/V.
#define AT2_LDS 163840

__global__ __launch_bounds__(512,1) void k_attn2(const u16* __restrict__ q1, const u16* __restrict__ k1,
                                                 const u16* __restrict__ vp, const float* __restrict__ temp,
                                                 u16* __restrict__ out){
  extern __shared__ char smemraw[];
  u16* Qs = (u16*)smemraw;       // [128][256] swz; later Vt (subtiled [256 w][64 g]); later Os
  u16* Ks = Qs + 32768;          // [64][256] swz: K tiles (even), then V tile
  u16* Ps = Ks + 16384;          // [128][256] swz; first 32KB doubles as K buf1 during QK
  const int t = threadIdx.x;
  const int l = t & 63;
  const int wv = t >> 6;
  const int c15 = l & 15, h = l >> 4;
  const int n = blockIdx.x;
  const int blk = ((n & 7) << 6) | (n >> 3);   // bijective (512 = 8*64): same-plane halves -> same XCD
  const int plane = blk >> 1, hf = blk & 1;
  const u16* qp  = q1 + (size_t)plane * PIX + hf*128*HW;
  const u16* kp  = k1 + (size_t)plane * PIX;
  const u16* vpp = vp + (size_t)plane * PIX;
  u16* op = out + (size_t)plane * PIX + hf*128*HW;
  const float tc = temp[plane & 127];

  // ---- stage Q (128x256) + K tile 0 (64x256 -> buf0 = Ks), swizzled ----
  #pragma unroll
  for (int i = 0; i < 8; ++i){
    int c = t + i*512; int row = c >> 5, bc = (c & 31) << 3;
    *(uint4*)(Qs + swz(row, bc)) = *(const uint4*)(qp + row*HW + bc);
  }
  #pragma unroll
  for (int i = 0; i < 4; ++i){
    int c = t + i*512; int row = c >> 5, bc = (c & 31) << 3;
    *(uint4*)(Ks + swz(row, bc)) = *(const uint4*)(kp + row*HW + bc);
  }
  __syncthreads();

  // ---- A-frags: this wave's 16 Q rows, full k=256 ----
  const int r_a = wv*16 + c15;
  s8v qa[8];
  #pragma unroll
  for (int ks = 0; ks < 8; ++ks)
    qa[ks] = *(const s8v*)(Qs + swz(r_a, ks*32 + h*8));

  f4v sacc[16];
  #pragma unroll
  for (int i = 0; i < 16; ++i) sacc[i] = (f4v){0.f,0.f,0.f,0.f};

  uint4 pf[4];
  // ---- scores: S[16r][256g], K-dim = w; K double-buffered (Ks / Ps[0:32KB]) ----
  #pragma unroll
  for (int gt = 0; gt < 4; ++gt){
    {  // prefetch next K tile (or V tile 0) into regs
      const u16* src = (gt < 3) ? (kp + (gt+1)*64*HW) : vpp;
      #pragma unroll
      for (int i = 0; i < 4; ++i){
        int c = t + i*512; int row = c >> 5, bc = (c & 31) << 3;
        pf[i] = *(const uint4*)(src + row*HW + bc);
      }
    }
    const u16* kb = (gt & 1) ? Ps : Ks;      // read buffer for this tile
    #pragma unroll
    for (int gi = 0; gi < 4; ++gi){
      f4v acc = sacc[gt*4 + gi];
      #pragma unroll
      for (int ks = 0; ks < 8; ++ks){
        s8v b = *(const s8v*)(kb + swz(gi*16 + c15, ks*32 + h*8));
        acc = __builtin_amdgcn_mfma_f32_16x16x32_bf16(qa[ks], b, acc, 0, 0, 0);
      }
      sacc[gt*4 + gi] = acc;
    }
    // write next tile into the OTHER buffer (no WAR with this tile's reads;
    // prior tile's reads of that buffer were fenced by the previous barrier)
    u16* kw = (gt & 1) ? Ks : Ps;
    #pragma unroll
    for (int i = 0; i < 4; ++i){
      int c = t + i*512; int row = c >> 5, bc = (c & 31) << 3;
      *(uint4*)(kw + swz(row, bc)) = pf[i];
    }
    __syncthreads();
  }

  // ---- softmax over g, fully in-register ----
  float mj[4] = {-1e30f,-1e30f,-1e30f,-1e30f};
  #pragma unroll
  for (int i = 0; i < 16; ++i)
    #pragma unroll
    for (int j = 0; j < 4; ++j){
      sacc[i][j] *= tc;
      mj[j] = fmaxf(mj[j], sacc[i][j]);
    }
  #pragma unroll
  for (int j = 0; j < 4; ++j){
    mj[j] = fmaxf(mj[j], __shfl_xor(mj[j], 1, 64));
    mj[j] = fmaxf(mj[j], __shfl_xor(mj[j], 2, 64));
    mj[j] = fmaxf(mj[j], __shfl_xor(mj[j], 4, 64));
    mj[j] = fmaxf(mj[j], __shfl_xor(mj[j], 8, 64));
  }
  float sj[4] = {0.f,0.f,0.f,0.f};
  #pragma unroll
  for (int i = 0; i < 16; ++i)
    #pragma unroll
    for (int j = 0; j < 4; ++j){
      float e = __expf(sacc[i][j] - mj[j]);
      sacc[i][j] = e;
      sj[j] += e;
    }
  #pragma unroll
  for (int j = 0; j < 4; ++j){
    sj[j] += __shfl_xor(sj[j], 1, 64);
    sj[j] += __shfl_xor(sj[j], 2, 64);
    sj[j] += __shfl_xor(sj[j], 4, 64);
    sj[j] += __shfl_xor(sj[j], 8, 64);
    sj[j] = 1.0f / sj[j];
  }
  #pragma unroll
  for (int i = 0; i < 16; ++i)
    #pragma unroll
    for (int j = 0; j < 4; ++j)
      Ps[swz(wv*16 + h*4 + j, i*16 + c15)] = f2bu(sacc[i][j] * sj[j]);
  __syncthreads();

  // ---- PV: out[16r][256w], K-dim = g (4 tiles of 64) ----
  f4v oacc[16];
  #pragma unroll
  for (int i = 0; i < 16; ++i) oacc[i] = (f4v){0.f,0.f,0.f,0.f};

  #pragma unroll
  for (int gt = 0; gt < 4; ++gt){
    if (gt < 3){
      #pragma unroll
      for (int i = 0; i < 4; ++i){
        int c = t + i*512; int row = c >> 5, bc = (c & 31) << 3;
        pf[i] = *(const uint4*)(vpp + (gt+1)*64*HW + row*HW + bc);
      }
    }
    // transpose Vs(Ks) [64g][256w] -> Vt(Qs) subtiled [256w][64g], 8x8 per thread, t<256
    if (t < 256){
      int gb = t >> 5, wb = t & 31;
      u32 rr[8][4];
      #pragma unroll
      for (int i = 0; i < 8; ++i){
        uint4 v = *(const uint4*)(Ks + (gb*8 + i)*256 + ((wb ^ i) << 3));
        rr[i][0] = v.x; rr[i][1] = v.y; rr[i][2] = v.z; rr[i][3] = v.w;
      }
      #pragma unroll
      for (int j = 0; j < 8; ++j){
        u32 sel = (j & 1) ? 0x07060302u : 0x05040100u;
        int jh = j >> 1;
        u32 o0 = __builtin_amdgcn_perm(rr[1][jh], rr[0][jh], sel);
        u32 o1 = __builtin_amdgcn_perm(rr[3][jh], rr[2][jh], sel);
        u32 o2 = __builtin_amdgcn_perm(rr[5][jh], rr[4][jh], sel);
        u32 o3 = __builtin_amdgcn_perm(rr[7][jh], rr[6][jh], sel);
        int w = wb*8 + j;
        *(uint4*)(Qs + vt_el(w, gb)) = make_uint4(o0, o1, o2, o3);
      }
    }
    __syncthreads();
    if (gt < 3){
      #pragma unroll
      for (int i = 0; i < 4; ++i){
        int c = t + i*512; int row = c >> 5, bc = (c & 31) << 3;
        *(uint4*)(Ks + swz(row, bc)) = pf[i];
      }
    }
    s8v pa[2];
    #pragma unroll
    for (int k2 = 0; k2 < 2; ++k2)
      pa[k2] = *(const s8v*)(Ps + swz(r_a, gt*64 + k2*32 + h*8));
    #pragma unroll
    for (int wt = 0; wt < 16; ++wt){
      f4v acc = oacc[wt];
      #pragma unroll
      for (int k2 = 0; k2 < 2; ++k2){
        int w = wt*16 + c15;
        s8v b = *(const s8v*)(Qs + vt_el(w, (k2 << 2) + h));
        acc = __builtin_amdgcn_mfma_f32_16x16x32_bf16(pa[k2], b, acc, 0, 0, 0);
      }
      oacc[wt] = acc;
    }
    __syncthreads();
  }

  // ---- stage output in LDS (Qs region), then coalesced global write ----
  #pragma unroll
  for (int wt = 0; wt < 16; ++wt)
    #pragma unroll
    for (int j = 0; j < 4; ++j)
      Qs[swz(wv*16 + h*4 + j, wt*16 + c15)] = f2bu(oacc[wt][j]);
  __syncthreads();
  #pragma unroll
  for (int i = 0; i < 8; ++i){
    int row = wv*16 + i*2 + (l >> 5);
    int bc = (l & 31) << 3;
    uint4 v = *(const uint4*)(Qs + swz(row, bc));
    *(uint4*)(op + row*HW + bc) = v;
  }
}

extern "C" void kernel_launch(void* const* d_in, const int* in_sizes, int n_in,
                              void* d_out, int out_size, void* d_ws, size_t ws_size,
                              hipStream_t stream){
  (void)in_sizes; (void)n_in; (void)out_size;
  if (ws_size < (size_t)WS_NEED) return;

  const float* x     = (const float*)d_in[0];
  const float* w_qkv = (const float*)d_in[1];
  const float* b_qkv = (const float*)d_in[2];
  const float* w_q   = (const float*)d_in[3];
  const float* b_q   = (const float*)d_in[4];
  const float* w_k   = (const float*)d_in[5];
  const float* b_k   = (const float*)d_in[6];
  const float* w_v1  = (const float*)d_in[7];
  const float* b_v1  = (const float*)d_in[8];
  const float* w_v2  = (const float*)d_in[9];
  const float* b_v2  = (const float*)d_in[10];
  const float* temp  = (const float*)d_in[11];
  const float* w_po  = (const float*)d_in[12];
  const float* b_po  = (const float*)d_in[13];

  char* ws = (char*)d_ws;
  u16*  qkv = (u16*)ws;                        // 768 planes
  u16*  q1  = (u16*)(ws + WS_T1);
  u16*  k1  = (u16*)(ws + WS_K1);
  u16*  vp  = (u16*)(ws + WS_VP);
  u16*  aout = qkv;                            // attn output over dead qkv planes 0..255
  u16*  wq_bf  = q1;                           // 96KB scratch in q1 region (dead until dwqk2)
  u16*  wpo_bf = k1;                           // 32KB scratch in k1 region (dead after attn2)
  float* out = (float*)d_out;

  (void)hipFuncSetAttribute((const void*)k_gemmP2<384, float, false>, hipFuncAttributeMaxDynamicSharedMemorySize, GP384_LDS);
  (void)hipFuncSetAttribute((const void*)k_gemmP2<128, u16, true>,   hipFuncAttributeMaxDynamicSharedMemorySize, GP128_LDS);

  k_wprep<<<192, 256, 0, stream>>>(w_qkv, wq_bf, 384*128);
  k_gemmP2<384, float, false><<<512, 512, GP384_LDS, stream>>>(x, wq_bf, b_qkv, 384, (void*)qkv);
  k_dwqk2<<<dim3(16, 128, 4), 256, 0, stream>>>(qkv, w_q, b_q, w_k, b_k, q1, k1);
  (void)hipFuncSetAttribute((const void*)k_mdc2, hipFuncAttributeMaxDynamicSharedMemorySize, MDC_LDS);
  k_mdc2<<<dim3(8, 64, 2), 256, MDC_LDS, stream>>>(qkv, w_v1, b_v1, w_v2, b_v2, vp);
  (void)hipFuncSetAttribute((const void*)k_attn2, hipFuncAttributeMaxDynamicSharedMemorySize, AT2_LDS);
  k_attn2<<<512, 512, AT2_LDS, stream>>>(q1, k1, vp, temp, aout);
  k_wprep<<<64, 256, 0, stream>>>(w_po, wpo_bf, 128*128);
  k_gemmP2<128, u16, true><<<512, 512, GP128_LDS, stream>>>(aout, wpo_bf, b_po, 128, (void*)out);
}

// Round 20
// 225.015 us; speedup vs baseline: 1.0205x; 1.0205x over previous
//
#include <hip/hip_runtime.h>

typedef unsigned short u16;
typedef unsigned int u32;

#define HW 256
#define PIX 65536

// workspace byte offsets
#define WS_T1   100663296ull
#define WS_K1   134217728ull
#define WS_VP   167772160ull
#define WS_NEED 201326592ull

typedef __attribute__((ext_vector_type(8))) short s8v;   // 8 bf16
typedef __attribute__((ext_vector_type(4))) float f4v;

__device__ __forceinline__ float bu2f(u16 u){ union{u32 i; float f;} x; x.i=((u32)u)<<16; return x.f; }
__device__ __forceinline__ u16 f2bu(float f){ union{float f; u32 i;} x; x.f=f; u32 i=x.i; return (u16)((i + 0x7FFFu + ((i>>16)&1u))>>16); }
__device__ __forceinline__ float sigm(float x){ return 1.0f/(1.0f+__expf(-x)); }
__device__ __forceinline__ u16 cvt_el(float v){ return f2bu(v); }
__device__ __forceinline__ u16 cvt_el(u16 v){ return v; }
// XOR swizzle for [R][256] u16 tiles (8-elem block granularity)
__device__ __forceinline__ int swz(int r, int c){ return r*256 + (((c>>3) ^ (r&7))<<3) + (c&7); }
// XOR swizzle for [256 p][128 c] u16 tiles (same family, stride 128)
__device__ __forceinline__ int pswz(int p, int c){ return (p<<7) + (((c>>3) ^ (p&7))<<3) + (c&7); }
// Vt subtile layout: conflict-free for both transpose-write and PV b-frag read
__device__ __forceinline__ int vt_el(int w, int gb){   // gb = g>>3
  int q = (w & 15) ^ gb ^ ((w >> 4) & 7);
  return ((w >> 4) << 10) + (gb << 7) + (q << 3);
}

// ---------------- weight prep: fp32 -> bf16, pre-swizzled to the GEMM's Wl image ----------------
__global__ __launch_bounds__(256) void k_wprep(const float* __restrict__ Wg, u16* __restrict__ G, int n){
  int i = blockIdx.x * 256 + threadIdx.x;
  if (i >= n) return;
  int o = i >> 7, c = i & 127;
  G[(o << 7) | (c ^ ((o & 7) << 3))] = f2bu(Wg[i]);
}

// ---------------- fused MFMA GEMM over plane-layout input (8 waves) ----------------
template<int OC, typename TIN, bool F32>
__global__ __launch_bounds__(512,1) void k_gemmP2(const TIN* __restrict__ in, const u16* __restrict__ Wbf,
                                                  const float* __restrict__ bias, int O_total,
                                                  void* __restrict__ outv){
  extern __shared__ u16 lds[];
  u16* Wl = lds;                 // [OC][128] swizzled (c ^ (o&7)<<3)
  u16* Xl = lds + OC*128;        // [256 p][128 c] pswz
  int t = threadIdx.x;
  {
    const uint4* Wq4 = (const uint4*)Wbf;
    uint4* Wl4 = (uint4*)Wl;
    #pragma unroll
    for (int i = t; i < OC*16; i += 512) Wl4[i] = Wq4[i];
  }
  int p_blk = blockIdx.x * 256;
  int b = p_blk >> 16;
  int p0 = p_blk & 65535;
  if (sizeof(TIN) == 4){
    int p = t & 255, half = (t >> 8) * 64;
    const float* col = (const float*)in + ((size_t)(b*128 + half))*PIX + p0 + p;
    #pragma unroll
    for (int c8 = 0; c8 < 8; ++c8){
      u32 pk[4];
      #pragma unroll
      for (int j = 0; j < 4; ++j){
        u16 v0 = f2bu(col[(size_t)(c8*8 + 2*j)*PIX]);
        u16 v1 = f2bu(col[(size_t)(c8*8 + 2*j + 1)*PIX]);
        pk[j] = (u32)v0 | ((u32)v1 << 16);
      }
      *(uint4*)(Xl + pswz(p, half + c8*8)) = make_uint4(pk[0],pk[1],pk[2],pk[3]);
    }
  } else {
    int p = (t & 127) * 2, quarter = (t >> 7) * 32;
    const u16* col = (const u16*)in + ((size_t)(b*128 + quarter))*PIX + p0 + p;
    #pragma unroll
    for (int c8 = 0; c8 < 4; ++c8){
      u32 va[4], vb[4];
      #pragma unroll
      for (int j = 0; j < 4; ++j){
        u32 w0 = *(const u32*)(col + (size_t)(c8*8 + 2*j)*PIX);
        u32 w1 = *(const u32*)(col + (size_t)(c8*8 + 2*j + 1)*PIX);
        va[j] = (w0 & 0xFFFFu) | (w1 << 16);
        vb[j] = (w0 >> 16) | (w1 & 0xFFFF0000u);
      }
      *(uint4*)(Xl + pswz(p,     quarter + c8*8)) = make_uint4(va[0],va[1],va[2],va[3]);
      *(uint4*)(Xl + pswz(p + 1, quarter + c8*8)) = make_uint4(vb[0],vb[1],vb[2],vb[3]);
    }
  }
  __syncthreads();

  int wv = t >> 6, l = t & 63;
  int lg = l >> 4, lr = l & 15;
  int p_in0 = p0 + wv*32 + lr;

  s8v bf[2][4];
  #pragma unroll
  for (int pt = 0; pt < 2; ++pt){
    int p = wv*32 + pt*16 + lr;
    #pragma unroll
    for (int ks = 0; ks < 4; ++ks)
      bf[pt][ks] = *(const s8v*)(Xl + pswz(p, ks*32 + lg*8));
  }

  for (int ot = 0; ot < OC / 16; ++ot){
    f4v acc[2];
    acc[0] = (f4v){0.f,0.f,0.f,0.f};
    acc[1] = (f4v){0.f,0.f,0.f,0.f};
    int o = (ot << 4) + lr;
    const u16* wl = Wl + (o << 7);
    int sw = (o & 7) << 3;
    #pragma unroll
    for (int ks = 0; ks < 4; ++ks){
      s8v a = *(const s8v*)(wl + ((((ks << 5) + (lg << 3)) ^ sw)));
      acc[0] = __builtin_amdgcn_mfma_f32_16x16x32_bf16(a, bf[0][ks], acc[0], 0, 0, 0);
      acc[1] = __builtin_amdgcn_mfma_f32_16x16x32_bf16(a, bf[1][ks], acc[1], 0, 0, 0);
    }
    #pragma unroll
    for (int j = 0; j < 4; ++j){
      int o_row = (ot << 4) + (lg << 2) + j;
      float bv = bias[o_row];
      size_t base = ((size_t)(b * O_total + o_row)) << 16;
      #pragma unroll
      for (int pt = 0; pt < 2; ++pt){
        if (F32){
          ((float*)outv)[base + p_in0 + pt*16] = acc[pt][j] + bv;
        } else {
          ((u16*)outv)[base + p_in0 + pt*16] = f2bu(acc[pt][j] + bv);
        }
      }
    }
  }
}
#define GP384_LDS ((384*128 + 256*128) * 2)   // 163840
#define GP128_LDS ((128*128 + 256*128) * 2)   // 98304

// ---------------- depthwise 3x3 on q,k + fused row L2-normalize (LDS tiled) ----------------
__global__ __launch_bounds__(256) void k_dwqk2(const u16* __restrict__ qkv,
                                               const float* __restrict__ w_q, const float* __restrict__ b_q,
                                               const float* __restrict__ w_k, const float* __restrict__ b_k,
                                               u16* __restrict__ q1, u16* __restrict__ k1){
  __shared__ u16 ins[18*272];
  int t = threadIdx.x;
  int chunk = blockIdx.x;
  int c = blockIdx.y;
  int which = blockIdx.z & 1, b = blockIdx.z >> 1;
  const u16* in = qkv + ((size_t)(b*384 + which*128 + c)) * PIX;

  #pragma unroll
  for (int i = t; i < 612; i += 256) ((uint4*)ins)[i] = make_uint4(0,0,0,0);
  __syncthreads();
  int r0 = chunk*16 - 1;
  for (int i = t; i < 576; i += 256){
    int j = i >> 5, k = i & 31;
    int r = r0 + j;
    if (r >= 0 && r < HW)
      *(uint4*)(ins + j*272 + 8 + k*8) = *(const uint4*)(in + r*HW + k*8);
  }
  __syncthreads();

  const float* wk = (which ? w_k : w_q) + c*9;
  float K0=wk[0],K1=wk[1],K2=wk[2],K3=wk[3],K4=wk[4],K5=wk[5],K6=wk[6],K7=wk[7],K8=wk[8];
  float bias = (which ? b_k : b_q)[c];

  int wv = t >> 6, l = t & 63;
  int cb = l * 4;
  float wr[3][6];
  auto ldrow = [&](int j, int slot){
    ushort4 m = *(const ushort4*)(ins + j*272 + 8 + cb);
    wr[slot][0] = bu2f(ins[j*272 + 7 + cb]);
    wr[slot][1] = bu2f(m.x); wr[slot][2] = bu2f(m.y);
    wr[slot][3] = bu2f(m.z); wr[slot][4] = bu2f(m.w);
    wr[slot][5] = bu2f(ins[j*272 + 12 + cb]);
  };
  int rb = wv * 4;
  ldrow(rb, 0); ldrow(rb+1, 1);
  u16* outp = (which ? k1 : q1) + ((size_t)(b*128 + c)) * PIX;
  #pragma unroll
  for (int s = 0; s < 4; ++s){
    ldrow(rb + s + 2, (s+2)%3);
    const float* T = wr[s%3];
    const float* M = wr[(s+1)%3];
    const float* Bo = wr[(s+2)%3];
    float o[4]; float ss = 0.f;
    #pragma unroll
    for (int d = 0; d < 4; ++d){
      float a = bias;
      a = fmaf(K0, T[d], a);  a = fmaf(K1, T[d+1], a);  a = fmaf(K2, T[d+2], a);
      a = fmaf(K3, M[d], a);  a = fmaf(K4, M[d+1], a);  a = fmaf(K5, M[d+2], a);
      a = fmaf(K6, Bo[d], a); a = fmaf(K7, Bo[d+1], a); a = fmaf(K8, Bo[d+2], a);
      o[d] = a;
      ss = fmaf(a, a, ss);
    }
    #pragma unroll
    for (int m = 1; m < 64; m <<= 1) ss += __shfl_xor(ss, m, 64);
    float sc = 1.0f / fmaxf(sqrtf(ss), 1e-12f);
    int row = chunk*16 + rb + s;
    ushort4 pk;
    pk.x = f2bu(o[0]*sc); pk.y = f2bu(o[1]*sc); pk.z = f2bu(o[2]*sc); pk.w = f2bu(o[3]*sc);
    *(ushort4*)(outp + row*HW + cb) = pk;
  }
}

// ---------------- MDC on v (LDS tiled, 32-row chunks) ----------------
#define MDC_LDS (2*36*272*2 + 34*272*4)   // 76160 B

__global__ __launch_bounds__(256,1) void k_mdc2(const u16* __restrict__ qkv,
                                                const float* __restrict__ w_v1, const float* __restrict__ b_v1,
                                                const float* __restrict__ w_v2, const float* __restrict__ b_v2,
                                                u16* __restrict__ vp){
  extern __shared__ char sm[];
  u16*   ins = (u16*)sm;                       // [2 ch][36 rows][272]
  float* x1s = (float*)(sm + 2*36*272*2);      // [34 rows][272]
  int t = threadIdx.x;
  int chunk = blockIdx.x;
  int g = blockIdx.y;
  int b = blockIdx.z;
  const u16* vbase = qkv + ((size_t)(b*384 + 256)) * PIX;

  #pragma unroll
  for (int i = t; i < 2*36*34; i += 256) ((uint4*)ins)[i] = make_uint4(0,0,0,0);
  for (int i = t; i < 34*68; i += 256) ((uint4*)x1s)[i] = make_uint4(0,0,0,0);
  __syncthreads();
  int r0 = chunk*32 - 2;
  #pragma unroll
  for (int ch = 0; ch < 2; ++ch){
    const u16* src = vbase + (size_t)(2*g + ch) * PIX;
    for (int i = t; i < 1152; i += 256){
      int j = i >> 5, k = i & 31;
      int r = r0 + j;
      if (r >= 0 && r < HW)
        *(uint4*)(ins + ch*36*272 + j*272 + 8 + k*8) = *(const uint4*)(src + r*HW + k*8);
    }
  }
  __syncthreads();

  float W1[18];
  #pragma unroll
  for (int i = 0; i < 18; ++i) W1[i] = w_v1[g*18 + i];
  float B1 = b_v1[g];
  int cb = t + 8;
  float win[2][3][3];
  #pragma unroll
  for (int ch = 0; ch < 2; ++ch)
    #pragma unroll
    for (int rr = 0; rr < 2; ++rr)
      #pragma unroll
      for (int k = 0; k < 3; ++k)
        win[ch][rr][k] = bu2f(ins[ch*36*272 + rr*272 + cb - 1 + k]);
  #pragma unroll
  for (int j = 0; j < 34; ++j){
    #pragma unroll
    for (int ch = 0; ch < 2; ++ch)
      #pragma unroll
      for (int k = 0; k < 3; ++k)
        win[ch][(j+2)%3][k] = bu2f(ins[ch*36*272 + (j+2)*272 + cb - 1 + k]);
    float v = B1;
    #pragma unroll
    for (int ch = 0; ch < 2; ++ch)
      #pragma unroll
      for (int i = 0; i < 3; ++i)
        #pragma unroll
        for (int k = 0; k < 3; ++k)
          v = fmaf(W1[ch*9 + i*3 + k], win[ch][(j+i)%3][k], v);
    int gr = chunk*32 - 1 + j;
    if (gr >= 0 && gr < HW) x1s[j*272 + cb] = v;
  }
  __syncthreads();

  float W2[9];
  #pragma unroll
  for (int i = 0; i < 9; ++i) W2[i] = w_v2[g*9 + i];
  float B2 = b_v2[g];
  const u16* vg   = vbase + (size_t)g * PIX;
  const u16* vg64 = vbase + (size_t)(64 + g) * PIX;
  u16* out0 = vp + ((size_t)(b*128 + g)) * PIX;
  u16* out1 = vp + ((size_t)(b*128 + 64 + g)) * PIX;
  float xw[3][3];
  #pragma unroll
  for (int rr = 0; rr < 2; ++rr)
    #pragma unroll
    for (int k = 0; k < 3; ++k)
      xw[rr][k] = x1s[rr*272 + cb - 1 + k];
  #pragma unroll
  for (int h = 0; h < 32; ++h){
    #pragma unroll
    for (int k = 0; k < 3; ++k)
      xw[(h+2)%3][k] = x1s[(h+2)*272 + cb - 1 + k];
    float x2 = B2;
    #pragma unroll
    for (int i = 0; i < 3; ++i)
      #pragma unroll
      for (int k = 0; k < 3; ++k)
        x2 = fmaf(W2[i*3 + k], xw[(h+i)%3][k], x2);
    int gr = chunk*32 + h;
    float g1 = sigm(bu2f(vg[gr*HW + t]));
    float g2 = sigm(bu2f(vg64[gr*HW + t]));
    float x1c = xw[(h+1)%3][1];
    out0[gr*HW + t] = f2bu(g1 * x1c);
    out1[gr*HW + t] = f2bu(g2 * x2);
  }
}

// ---------------- MFMA per-(b,c) row attention (K-dbuf QK + XCD grouping + Q-frags from global) ----------------
// block = (plane, half of 128 q-rows); 512 blocks x 512 threads, 160KB LDS
#define AT2_LDS 163840

__global__ __launch_bounds__(512,1) void k_attn2(const u16* __restrict__ q1, const u16* __restrict__ k1,
                                                 const u16* __restrict__ vp, const float* __restrict__ temp,
                                                 u16* __restrict__ out){
  extern __shared__ char smemraw[];
  u16* Qs = (u16*)smemraw;       // Vt (subtiled [256 w][64 g]) during PV; Os at end
  u16* Ks = Qs + 32768;          // [64][256] swz: K tiles (even), then V tile
  u16* Ps = Ks + 16384;          // [128][256] swz; first 32KB doubles as K buf1 during QK
  const int t = threadIdx.x;
  const int l = t & 63;
  const int wv = t >> 6;
  const int c15 = l & 15, h = l >> 4;
  const int n = blockIdx.x;
  const int blk = ((n & 7) << 6) | (n >> 3);   // bijective (512 = 8*64): same-plane halves -> same XCD
  const int plane = blk >> 1, hf = blk & 1;
  const u16* qp  = q1 + (size_t)plane * PIX + hf*128*HW;
  const u16* kp  = k1 + (size_t)plane * PIX;
  const u16* vpp = vp + (size_t)plane * PIX;
  u16* op = out + (size_t)plane * PIX + hf*128*HW;
  const float tc = temp[plane & 127];

  // ---- stage K tile 0 (64x256 -> buf0 = Ks), swizzled; Q is NOT staged (A-frags from global) ----
  #pragma unroll
  for (int i = 0; i < 4; ++i){
    int c = t + i*512; int row = c >> 5, bc = (c & 31) << 3;
    *(uint4*)(Ks + swz(row, bc)) = *(const uint4*)(kp + row*HW + bc);
  }

  // ---- A-frags: this wave's 16 Q rows, full k=256, direct per-lane global loads (L2-hot) ----
  const int r_a = wv*16 + c15;
  const u16* qrow = qp + r_a*HW;
  s8v qa[8];
  #pragma unroll
  for (int ks = 0; ks < 8; ++ks)
    qa[ks] = *(const s8v*)(qrow + ks*32 + h*8);
  __syncthreads();

  f4v sacc[16];
  #pragma unroll
  for (int i = 0; i < 16; ++i) sacc[i] = (f4v){0.f,0.f,0.f,0.f};

  uint4 pf[4];
  // ---- scores: S[16r][256g], K-dim = w; K double-buffered (Ks / Ps[0:32KB]) ----
  #pragma unroll
  for (int gt = 0; gt < 4; ++gt){
    {  // prefetch next K tile (or V tile 0) into regs
      const u16* src = (gt < 3) ? (kp + (gt+1)*64*HW) : vpp;
      #pragma unroll
      for (int i = 0; i < 4; ++i){
        int c = t + i*512; int row = c >> 5, bc = (c & 31) << 3;
        pf[i] = *(const uint4*)(src + row*HW + bc);
      }
    }
    const u16* kb = (gt & 1) ? Ps : Ks;      // read buffer for this tile
    #pragma unroll
    for (int gi = 0; gi < 4; ++gi){
      f4v acc = sacc[gt*4 + gi];
      #pragma unroll
      for (int ks = 0; ks < 8; ++ks){
        s8v b = *(const s8v*)(kb + swz(gi*16 + c15, ks*32 + h*8));
        acc = __builtin_amdgcn_mfma_f32_16x16x32_bf16(qa[ks], b, acc, 0, 0, 0);
      }
      sacc[gt*4 + gi] = acc;
    }
    // write next tile into the OTHER buffer (no WAR with this tile's reads;
    // prior tile's reads of that buffer were fenced by the previous barrier)
    u16* kw = (gt & 1) ? Ks : Ps;
    #pragma unroll
    for (int i = 0; i < 4; ++i){
      int c = t + i*512; int row = c >> 5, bc = (c & 31) << 3;
      *(uint4*)(kw + swz(row, bc)) = pf[i];
    }
    __syncthreads();
  }

  // ---- softmax over g, fully in-register ----
  float mj[4] = {-1e30f,-1e30f,-1e30f,-1e30f};
  #pragma unroll
  for (int i = 0; i < 16; ++i)
    #pragma unroll
    for (int j = 0; j < 4; ++j){
      sacc[i][j] *= tc;
      mj[j] = fmaxf(mj[j], sacc[i][j]);
    }
  #pragma unroll
  for (int j = 0; j < 4; ++j){
    mj[j] = fmaxf(mj[j], __shfl_xor(mj[j], 1, 64));
    mj[j] = fmaxf(mj[j], __shfl_xor(mj[j], 2, 64));
    mj[j] = fmaxf(mj[j], __shfl_xor(mj[j], 4, 64));
    mj[j] = fmaxf(mj[j], __shfl_xor(mj[j], 8, 64));
  }
  float sj[4] = {0.f,0.f,0.f,0.f};
  #pragma unroll
  for (int i = 0; i < 16; ++i)
    #pragma unroll
    for (int j = 0; j < 4; ++j){
      float e = __expf(sacc[i][j] - mj[j]);
      sacc[i][j] = e;
      sj[j] += e;
    }
  #pragma unroll
  for (int j = 0; j < 4; ++j){
    sj[j] += __shfl_xor(sj[j], 1, 64);
    sj[j] += __shfl_xor(sj[j], 2, 64);
    sj[j] += __shfl_xor(sj[j], 4, 64);
    sj[j] += __shfl_xor(sj[j], 8, 64);
    sj[j] = 1.0f / sj[j];
  }
  #pragma unroll
  for (int i = 0; i < 16; ++i)
    #pragma unroll
    for (int j = 0; j < 4; ++j)
      Ps[swz(wv*16 + h*4 + j, i*16 + c15)] = f2bu(sacc[i][j] * sj[j]);
  __syncthreads();

  // ---- PV: out[16r][256w], K-dim = g (4 tiles of 64) ----
  f4v oacc[16];
  #pragma unroll
  for (int i = 0; i < 16; ++i) oacc[i] = (f4v){0.f,0.f,0.f,0.f};

  #pragma unroll
  for (int gt = 0; gt < 4; ++gt){
    if (gt < 3){
      #pragma unroll
      for (int i = 0; i < 4; ++i){
        int c = t + i*512; int row = c >> 5, bc = (c & 31) << 3;
        pf[i] = *(const uint4*)(vpp + (gt+1)*64*HW + row*HW + bc);
      }
    }
    // transpose Vs(Ks) [64g][256w] -> Vt(Qs) subtiled [256w][64g], 8x8 per thread, t<256
    if (t < 256){
      int gb = t >> 5, wb = t & 31;
      u32 rr[8][4];
      #pragma unroll
      for (int i = 0; i < 8; ++i){
        uint4 v = *(const uint4*)(Ks + (gb*8 + i)*256 + ((wb ^ i) << 3));
        rr[i][0] = v.x; rr[i][1] = v.y; rr[i][2] = v.z; rr[i][3] = v.w;
      }
      #pragma unroll
      for (int j = 0; j < 8; ++j){
        u32 sel = (j & 1) ? 0x07060302u : 0x05040100u;
        int jh = j >> 1;
        u32 o0 = __builtin_amdgcn_perm(rr[1][jh], rr[0][jh], sel);
        u32 o1 = __builtin_amdgcn_perm(rr[3][jh], rr[2][jh], sel);
        u32 o2 = __builtin_amdgcn_perm(rr[5][jh], rr[4][jh], sel);
        u32 o3 = __builtin_amdgcn_perm(rr[7][jh], rr[6][jh], sel);
        int w = wb*8 + j;
        *(uint4*)(Qs + vt_el(w, gb)) = make_uint4(o0, o1, o2, o3);
      }
    }
    __syncthreads();
    if (gt < 3){
      #pragma unroll
      for (int i = 0; i < 4; ++i){
        int c = t + i*512; int row = c >> 5, bc = (c & 31) << 3;
        *(uint4*)(Ks + swz(row, bc)) = pf[i];
      }
    }
    s8v pa[2];
    #pragma unroll
    for (int k2 = 0; k2 < 2; ++k2)
      pa[k2] = *(const s8v*)(Ps + swz(r_a, gt*64 + k2*32 + h*8));
    #pragma unroll
    for (int wt = 0; wt < 16; ++wt){
      f4v acc = oacc[wt];
      #pragma unroll
      for (int k2 = 0; k2 < 2; ++k2){
        int w = wt*16 + c15;
        s8v b = *(const s8v*)(Qs + vt_el(w, (k2 << 2) + h));
        acc = __builtin_amdgcn_mfma_f32_16x16x32_bf16(pa[k2], b, acc, 0, 0, 0);
      }
      oacc[wt] = acc;
    }
    __syncthreads();
  }

  // ---- stage output in LDS (Qs region), then coalesced global write ----
  #pragma unroll
  for (int wt = 0; wt < 16; ++wt)
    #pragma unroll
    for (int j = 0; j < 4; ++j)
      Qs[swz(wv*16 + h*4 + j, wt*16 + c15)] = f2bu(oacc[wt][j]);
  __syncthreads();
  #pragma unroll
  for (int i = 0; i < 8; ++i){
    int row = wv*16 + i*2 + (l >> 5);
    int bc = (l & 31) << 3;
    uint4 v = *(const uint4*)(Qs + swz(row, bc));
    *(uint4*)(op + row*HW + bc) = v;
  }
}

extern "C" void kernel_launch(void* const* d_in, const int* in_sizes, int n_in,
                              void* d_out, int out_size, void* d_ws, size_t ws_size,
                              hipStream_t stream){
  (void)in_sizes; (void)n_in; (void)out_size;
  if (ws_size < (size_t)WS_NEED) return;

  const float* x     = (const float*)d_in[0];
  const float* w_qkv = (const float*)d_in[1];
  const float* b_qkv = (const float*)d_in[2];
  const float* w_q   = (const float*)d_in[3];
  const float* b_q   = (const float*)d_in[4];
  const float* w_k   = (const float*)d_in[5];
  const float* b_k   = (const float*)d_in[6];
  const float* w_v1  = (const float*)d_in[7];
  const float* b_v1  = (const float*)d_in[8];
  const float* w_v2  = (const float*)d_in[9];
  const float* b_v2  = (const float*)d_in[10];
  const float* temp  = (const float*)d_in[11];
  const float* w_po  = (const float*)d_in[12];
  const float* b_po  = (const float*)d_in[13];

  char* ws = (char*)d_ws;
  u16*  qkv = (u16*)ws;                        // 768 planes
  u16*  q1  = (u16*)(ws + WS_T1);
  u16*  k1  = (u16*)(ws + WS_K1);
  u16*  vp  = (u16*)(ws + WS_VP);
  u16*  aout = qkv;                            // attn output over dead qkv planes 0..255
  u16*  wq_bf  = q1;                           // 96KB scratch in q1 region (dead until dwqk2)
  u16*  wpo_bf = k1;                           // 32KB scratch in k1 region (dead after attn2)
  float* out = (float*)d_out;

  (void)hipFuncSetAttribute((const void*)k_gemmP2<384, float, false>, hipFuncAttributeMaxDynamicSharedMemorySize, GP384_LDS);
  (void)hipFuncSetAttribute((const void*)k_gemmP2<128, u16, true>,   hipFuncAttributeMaxDynamicSharedMemorySize, GP128_LDS);

  k_wprep<<<192, 256, 0, stream>>>(w_qkv, wq_bf, 384*128);
  k_gemmP2<384, float, false><<<512, 512, GP384_LDS, stream>>>(x, wq_bf, b_qkv, 384, (void*)qkv);
  k_dwqk2<<<dim3(16, 128, 4), 256, 0, stream>>>(qkv, w_q, b_q, w_k, b_k, q1, k1);
  (void)hipFuncSetAttribute((const void*)k_mdc2, hipFuncAttributeMaxDynamicSharedMemorySize, MDC_LDS);
  k_mdc2<<<dim3(8, 64, 2), 256, MDC_LDS, stream>>>(qkv, w_v1, b_v1, w_v2, b_v2, vp);
  (void)hipFuncSetAttribute((const void*)k_attn2, hipFuncAttributeMaxDynamicSharedMemorySize, AT2_LDS);
  k_attn2<<<512, 512, AT2_LDS, stream>>>(q1, k1, vp, temp, aout);
  k_wprep<<<64, 256, 0, stream>>>(w_po, wpo_bf, 128*128);
  k_gemmP2<128, u16, true><<<512, 512, GP128_LDS, stream>>>(aout, wpo_bf, b_po, 128, (void*)out);
}